// Round 8
// baseline (399.584 us; speedup 1.0000x reference)
//
#include <hip/hip_runtime.h>

#define NUM_E   2048
#define DIM     64
#define NROWS   32768            // 32*32*32
#define NELEM   2097152          // NROWS*DIM

// numpy pairwise_sum for n=64 of squares: 8 accumulators + tree combine.
// contract(off) so products round to f32 before the adds (matches np: flat*flat
// materialized, then summed).
__device__ __forceinline__ float np_sumsq64(const float* z) {
#pragma clang fp contract(off)
    float r[8];
    #pragma unroll
    for (int j = 0; j < 8; ++j) r[j] = z[j] * z[j];
    #pragma unroll
    for (int i = 8; i < 64; i += 8) {
        #pragma unroll
        for (int j = 0; j < 8; ++j) r[j] += z[i + j] * z[i + j];
    }
    return ((r[0] + r[1]) + (r[2] + r[3])) + ((r[4] + r[5]) + (r[6] + r[7]));
}

// per-code ||e||^2, numpy-bitwise
__global__ void se_kernel(const float* __restrict__ cb, float* __restrict__ se) {
    int k = blockIdx.x * blockDim.x + threadIdx.x;
    if (k < NUM_E) {
        float z[DIM];
        #pragma unroll
        for (int d = 0; d < DIM; ++d) z[d] = cb[(size_t)k * DIM + d];
        se[k] = np_sumsq64(z);
    }
}

// block: 1024 threads = 16 waves; 64 rows per block; wave w scans codes
// [w*128, w*128+128) for all 64 rows (one row per lane, z in VGPRs).
//
// KEY: z is loaded via VOLATILE scalar loads. Rounds 1/3/4/7 proved the
// backend rematerializes ANY ordinary load (LDS or global) into the scan loop
// rather than hold 64 live VGPRs — fences, waves_per_eu, and removing the LDS
// copy all failed (VGPR_Count stuck at 44-52, dur 191-243us, loop re-reads
// ~17GB from the LDS/L1 pipe). Volatile accesses are side-effecting: the
// compiler may not duplicate or sink them, so the 64 values MUST stay
// resident. waves_per_eu(4,4) raises the budget to 128 VGPRs so they sit in
// registers, not scratch.
__global__ __launch_bounds__(1024)
__attribute__((amdgpu_waves_per_eu(4, 4))) void vq_main(
        const float* __restrict__ x, const float* __restrict__ cb,
        const float* __restrict__ se, float* __restrict__ out_q,
        float* __restrict__ out_idx, float* __restrict__ loss_accum,
        unsigned int* __restrict__ counts) {
    __shared__ float red_d[16 * 64];
    __shared__ int   red_i[16 * 64];
    __shared__ int   ids[64];
    __shared__ float lred[16];

    const int t    = threadIdx.x;
    const int lane = t & 63;
    const int w    = t >> 6;
    const int brow = blockIdx.x * 64;

    // this lane's row -> registers via volatile loads (non-duplicable)
    float z[DIM];
    {
        const volatile float* xr = x + (size_t)(brow + lane) * DIM;
        #pragma unroll
        for (int d = 0; d < DIM; ++d) z[d] = xr[d];
    }

    const float sz = np_sumsq64(z);

    // wave-uniform code chunk -> scalar (s_load) path for cb/se
    const int c0 = __builtin_amdgcn_readfirstlane(w) * 128;

    float best = 3.4e38f;
    int   bidx = 0;
    #pragma unroll 2
    for (int c = 0; c < 128; ++c) {
        const int k = c0 + c;
        const float* e = cb + (size_t)k * DIM;
        float dot = 0.0f;                  // sequential chain ~ BLAS microkernel
        #pragma unroll
        for (int d = 0; d < DIM; ++d) dot = fmaf(z[d], e[d], dot);
        float dist;
        {
#pragma clang fp contract(off)
            float t1 = sz + se[k];         // same op order as reference
            dist = t1 - 2.0f * dot;
        }
        if (dist < best) { best = dist; bidx = k; }   // strict <: first-index ties
    }
    red_d[w * 64 + lane] = best;
    red_i[w * 64 + lane] = bidx;
    __syncthreads();

    // wave 0 reduces 16 chunks per row (ascending chunk = ascending code index)
    if (t < 64) {
        float bd = red_d[t];
        int   bi = red_i[t];
        #pragma unroll
        for (int w2 = 1; w2 < 16; ++w2) {
            float d2 = red_d[w2 * 64 + t];
            if (d2 < bd) { bd = d2; bi = red_i[w2 * 64 + t]; }
        }
        ids[t] = bi;
        out_idx[brow + t] = (float)bi;
        atomicAdd(&counts[bi], 1u);
    }
    __syncthreads();

    // quantized_st = x + (q - x) with the reference's exact rounding; x re-read
    // coalesced from global (L2-hot). One float4 per thread = 4096 elems/block.
    float lsum = 0.0f;
    {
        const int r  = t >> 4;         // row within block
        const int d4 = t & 15;         // float4 index within row
        float4 xv4 = ((const float4*)(x + (size_t)brow * DIM))[t];
        float4 q4  = ((const float4*)(cb + (size_t)ids[r] * DIM))[d4];
        float4 o;
        {
#pragma clang fp contract(off)
            o.x = xv4.x + (q4.x - xv4.x);
            o.y = xv4.y + (q4.y - xv4.y);
            o.z = xv4.z + (q4.z - xv4.z);
            o.w = xv4.w + (q4.w - xv4.w);
        }
        ((float4*)(out_q + (size_t)brow * DIM))[t] = o;
        float dx = xv4.x - q4.x, dy = xv4.y - q4.y;
        float dz = xv4.z - q4.z, dw = xv4.w - q4.w;
        lsum = fmaf(dx, dx, lsum); lsum = fmaf(dy, dy, lsum);
        lsum = fmaf(dz, dz, lsum); lsum = fmaf(dw, dw, lsum);
    }
    #pragma unroll
    for (int off = 32; off; off >>= 1) lsum += __shfl_down(lsum, off, 64);
    if (lane == 0) lred[w] = lsum;
    __syncthreads();
    if (t == 0) {
        float s = 0.0f;
        #pragma unroll
        for (int i = 0; i < 16; ++i) s += lred[i];
        atomicAdd(loss_accum, s);
    }
}

__global__ void finalize(const unsigned int* __restrict__ counts,
                         const float* __restrict__ loss_accum,
                         float* __restrict__ out_scalars) {
    __shared__ float partial[256];
    int t = threadIdx.x;
    float s = 0.0f;
    for (int i = t; i < NUM_E; i += 256) {
        float p = (float)counts[i] * (1.0f / 32768.0f);
        s += p * logf(p + 1e-10f);
    }
    partial[t] = s;
    __syncthreads();
    for (int off = 128; off; off >>= 1) {
        if (t < off) partial[t] += partial[t + off];
        __syncthreads();
    }
    if (t == 0) {
        float loss = *loss_accum * (1.0f / (float)NELEM);
        out_scalars[0] = loss;            // vq_loss
        out_scalars[1] = loss;            // commit_loss (identical by source)
        out_scalars[2] = expf(-partial[0]);  // perplexity
    }
}

extern "C" void kernel_launch(void* const* d_in, const int* in_sizes, int n_in,
                              void* d_out, int out_size, void* d_ws, size_t ws_size,
                              hipStream_t stream) {
    const float* x  = (const float*)d_in[0];
    const float* cb = (const float*)d_in[1];

    float* out_q       = (float*)d_out;               // [0, 2097152)
    float* out_scalars = (float*)d_out + NELEM;       // vq, commit, perplexity
    float* out_idx     = (float*)d_out + NELEM + 3;   // 32768 indices as f32

    unsigned int* counts   = (unsigned int*)d_ws;                       // 8 KB
    float*        loss_acc = (float*)((char*)d_ws + 8192);              // 4 B
    float*        se       = (float*)((char*)d_ws + 8448);              // 8 KB

    hipMemsetAsync(d_ws, 0, 8448, stream);
    se_kernel<<<dim3(8), dim3(256), 0, stream>>>(cb, se);
    vq_main<<<dim3(512), dim3(1024), 0, stream>>>(x, cb, se, out_q, out_idx,
                                                  loss_acc, counts);
    finalize<<<dim3(1), dim3(256), 0, stream>>>(counts, loss_acc, out_scalars);
}

// Round 9
// 257.191 us; speedup vs baseline: 1.5536x; 1.5536x over previous
//
#include <hip/hip_runtime.h>

#define NUM_E   2048
#define DIM     64
#define NROWS   32768            // 32*32*32
#define NELEM   2097152          // NROWS*DIM

// numpy pairwise_sum for n=64 of squares: 8 accumulators + tree combine.
// contract(off) so products round to f32 before the adds (matches np: flat*flat
// materialized, then summed).
__device__ __forceinline__ float np_sumsq64(const float* z) {
#pragma clang fp contract(off)
    float r[8];
    #pragma unroll
    for (int j = 0; j < 8; ++j) r[j] = z[j] * z[j];
    #pragma unroll
    for (int i = 8; i < 64; i += 8) {
        #pragma unroll
        for (int j = 0; j < 8; ++j) r[j] += z[i + j] * z[i + j];
    }
    return ((r[0] + r[1]) + (r[2] + r[3])) + ((r[4] + r[5]) + (r[6] + r[7]));
}

// per-code ||e||^2, numpy-bitwise
__global__ void se_kernel(const float* __restrict__ cb, float* __restrict__ se) {
    int k = blockIdx.x * blockDim.x + threadIdx.x;
    if (k < NUM_E) {
        float z[DIM];
        #pragma unroll
        for (int d = 0; d < DIM; ++d) z[d] = cb[(size_t)k * DIM + d];
        se[k] = np_sumsq64(z);
    }
}

// 16-step FMA chain in asm: acc += e[j]*z[j], j ascending. v_fmac_f32 is
// D += S0*S1 at fma precision, src0 may be SGPR (e, wave-uniform), vsrc1 is
// VGPR (z). Bitwise == fmaf(z[j], e[j], acc) sequential chain.
// KEY: the 16 z operands are asm INPUTS -> they MUST be materialized in VGPRs
// at every iteration. asm is never rematerializable, so the compiler cannot
// re-stream z from memory inside the scan loop (the failure mode of rounds
// 1/3/4/7/8: VGPR_Count stuck at 44-52, z re-read from LDS/L1 128x, 191-351us).
#define DOT16(ACC, ZP, EP)                                                    \
    asm("v_fmac_f32 %0, %17, %1\n\t"                                          \
        "v_fmac_f32 %0, %18, %2\n\t"                                          \
        "v_fmac_f32 %0, %19, %3\n\t"                                          \
        "v_fmac_f32 %0, %20, %4\n\t"                                          \
        "v_fmac_f32 %0, %21, %5\n\t"                                          \
        "v_fmac_f32 %0, %22, %6\n\t"                                          \
        "v_fmac_f32 %0, %23, %7\n\t"                                          \
        "v_fmac_f32 %0, %24, %8\n\t"                                          \
        "v_fmac_f32 %0, %25, %9\n\t"                                          \
        "v_fmac_f32 %0, %26, %10\n\t"                                         \
        "v_fmac_f32 %0, %27, %11\n\t"                                         \
        "v_fmac_f32 %0, %28, %12\n\t"                                         \
        "v_fmac_f32 %0, %29, %13\n\t"                                         \
        "v_fmac_f32 %0, %30, %14\n\t"                                         \
        "v_fmac_f32 %0, %31, %15\n\t"                                         \
        "v_fmac_f32 %0, %32, %16\n\t"                                         \
        : "+v"(ACC)                                                           \
        : "v"((ZP)[0]),  "v"((ZP)[1]),  "v"((ZP)[2]),  "v"((ZP)[3]),          \
          "v"((ZP)[4]),  "v"((ZP)[5]),  "v"((ZP)[6]),  "v"((ZP)[7]),          \
          "v"((ZP)[8]),  "v"((ZP)[9]),  "v"((ZP)[10]), "v"((ZP)[11]),         \
          "v"((ZP)[12]), "v"((ZP)[13]), "v"((ZP)[14]), "v"((ZP)[15]),         \
          "s"((EP)[0]),  "s"((EP)[1]),  "s"((EP)[2]),  "s"((EP)[3]),          \
          "s"((EP)[4]),  "s"((EP)[5]),  "s"((EP)[6]),  "s"((EP)[7]),          \
          "s"((EP)[8]),  "s"((EP)[9]),  "s"((EP)[10]), "s"((EP)[11]),         \
          "s"((EP)[12]), "s"((EP)[13]), "s"((EP)[14]), "s"((EP)[15]))

// block: 1024 threads = 16 waves; 64 rows per block; wave w scans codes
// [w*128, w*128+128) for all 64 rows (one row per lane, z forced into VGPRs
// by the DOT16 asm). waves_per_eu(4,8): 128-VGPR budget (z64 + ~40 working).
__global__ __launch_bounds__(1024)
__attribute__((amdgpu_waves_per_eu(4, 8))) void vq_main(
        const float* __restrict__ x, const float* __restrict__ cb,
        const float* __restrict__ se, float* __restrict__ out_q,
        float* __restrict__ out_idx, float* __restrict__ loss_accum,
        unsigned int* __restrict__ counts) {
    __shared__ float red_d[16 * 64];
    __shared__ int   red_i[16 * 64];
    __shared__ int   ids[64];
    __shared__ float lred[16];

    const int t    = threadIdx.x;
    const int lane = t & 63;
    const int w    = t >> 6;
    const int brow = blockIdx.x * 64;

    // this lane's row straight from global into registers (16 x float4)
    float z[DIM];
    {
        const float4* xr = (const float4*)(x + (size_t)(brow + lane) * DIM);
        #pragma unroll
        for (int i = 0; i < 16; ++i) {
            float4 v = xr[i];
            z[i * 4 + 0] = v.x; z[i * 4 + 1] = v.y;
            z[i * 4 + 2] = v.z; z[i * 4 + 3] = v.w;
        }
    }

    const float sz = np_sumsq64(z);

    // wave-uniform code chunk -> scalar (s_load) path for cb/se
    const int c0 = __builtin_amdgcn_readfirstlane(w) * 128;

    float best = 3.4e38f;
    int   bidx = 0;
    #pragma unroll 2
    for (int c = 0; c < 128; ++c) {
        const int k = c0 + c;
        const float* e = cb + (size_t)k * DIM;
        float dot = 0.0f;              // sequential fma chain, d = 0..63
        DOT16(dot, (z +  0), (e +  0));
        DOT16(dot, (z + 16), (e + 16));
        DOT16(dot, (z + 32), (e + 32));
        DOT16(dot, (z + 48), (e + 48));
        float dist;
        {
#pragma clang fp contract(off)
            float t1 = sz + se[k];     // same op order as reference
            dist = t1 - 2.0f * dot;
        }
        if (dist < best) { best = dist; bidx = k; }   // strict <: first-index ties
    }
    red_d[w * 64 + lane] = best;
    red_i[w * 64 + lane] = bidx;
    __syncthreads();

    // wave 0 reduces 16 chunks per row (ascending chunk = ascending code index)
    if (t < 64) {
        float bd = red_d[t];
        int   bi = red_i[t];
        #pragma unroll
        for (int w2 = 1; w2 < 16; ++w2) {
            float d2 = red_d[w2 * 64 + t];
            if (d2 < bd) { bd = d2; bi = red_i[w2 * 64 + t]; }
        }
        ids[t] = bi;
        out_idx[brow + t] = (float)bi;
        atomicAdd(&counts[bi], 1u);
    }
    __syncthreads();

    // quantized_st = x + (q - x) with the reference's exact rounding; x re-read
    // coalesced from global (L2-hot). One float4 per thread = 4096 elems/block.
    float lsum = 0.0f;
    {
        const int r  = t >> 4;         // row within block
        const int d4 = t & 15;         // float4 index within row
        float4 xv4 = ((const float4*)(x + (size_t)brow * DIM))[t];
        float4 q4  = ((const float4*)(cb + (size_t)ids[r] * DIM))[d4];
        float4 o;
        {
#pragma clang fp contract(off)
            o.x = xv4.x + (q4.x - xv4.x);
            o.y = xv4.y + (q4.y - xv4.y);
            o.z = xv4.z + (q4.z - xv4.z);
            o.w = xv4.w + (q4.w - xv4.w);
        }
        ((float4*)(out_q + (size_t)brow * DIM))[t] = o;
        float dx = xv4.x - q4.x, dy = xv4.y - q4.y;
        float dz = xv4.z - q4.z, dw = xv4.w - q4.w;
        lsum = fmaf(dx, dx, lsum); lsum = fmaf(dy, dy, lsum);
        lsum = fmaf(dz, dz, lsum); lsum = fmaf(dw, dw, lsum);
    }
    #pragma unroll
    for (int off = 32; off; off >>= 1) lsum += __shfl_down(lsum, off, 64);
    if (lane == 0) lred[w] = lsum;
    __syncthreads();
    if (t == 0) {
        float s = 0.0f;
        #pragma unroll
        for (int i = 0; i < 16; ++i) s += lred[i];
        atomicAdd(loss_accum, s);
    }
}

__global__ void finalize(const unsigned int* __restrict__ counts,
                         const float* __restrict__ loss_accum,
                         float* __restrict__ out_scalars) {
    __shared__ float partial[256];
    int t = threadIdx.x;
    float s = 0.0f;
    for (int i = t; i < NUM_E; i += 256) {
        float p = (float)counts[i] * (1.0f / 32768.0f);
        s += p * logf(p + 1e-10f);
    }
    partial[t] = s;
    __syncthreads();
    for (int off = 128; off; off >>= 1) {
        if (t < off) partial[t] += partial[t + off];
        __syncthreads();
    }
    if (t == 0) {
        float loss = *loss_accum * (1.0f / (float)NELEM);
        out_scalars[0] = loss;            // vq_loss
        out_scalars[1] = loss;            // commit_loss (identical by source)
        out_scalars[2] = expf(-partial[0]);  // perplexity
    }
}

extern "C" void kernel_launch(void* const* d_in, const int* in_sizes, int n_in,
                              void* d_out, int out_size, void* d_ws, size_t ws_size,
                              hipStream_t stream) {
    const float* x  = (const float*)d_in[0];
    const float* cb = (const float*)d_in[1];

    float* out_q       = (float*)d_out;               // [0, 2097152)
    float* out_scalars = (float*)d_out + NELEM;       // vq, commit, perplexity
    float* out_idx     = (float*)d_out + NELEM + 3;   // 32768 indices as f32

    unsigned int* counts   = (unsigned int*)d_ws;                       // 8 KB
    float*        loss_acc = (float*)((char*)d_ws + 8192);              // 4 B
    float*        se       = (float*)((char*)d_ws + 8448);              // 8 KB

    hipMemsetAsync(d_ws, 0, 8448, stream);
    se_kernel<<<dim3(8), dim3(256), 0, stream>>>(cb, se);
    vq_main<<<dim3(512), dim3(1024), 0, stream>>>(x, cb, se, out_q, out_idx,
                                                  loss_acc, counts);
    finalize<<<dim3(1), dim3(256), 0, stream>>>(counts, loss_acc, out_scalars);
}